// Round 13
// baseline (257.821 us; speedup 1.0000x reference)
//
#include <hip/hip_runtime.h>
#include <hip/hip_bf16.h>
#include <hip/hip_cooperative_groups.h>

namespace cg = cooperative_groups;

#define B_N 16384
#define D_K 128
#define NSPLIT 8
#define CPS 2048
#define FGRID 512   // 2 blocks/CU x 256 CU: exact cooperative co-residency

typedef __bf16 bf16x8 __attribute__((ext_vector_type(8)));
typedef float f32x4 __attribute__((ext_vector_type(4)));
typedef float f32x2 __attribute__((ext_vector_type(2)));

#if defined(__has_builtin)
#if __has_builtin(__builtin_amdgcn_exp2f)
#define EXP2F(x) __builtin_amdgcn_exp2f(x)
#else
#define EXP2F(x) exp2f(x)
#endif
#else
#define EXP2F(x) exp2f(x)
#endif

__device__ __forceinline__ void gload_lds16(const void* g, void* l) {
  __builtin_amdgcn_global_load_lds(
      (const __attribute__((address_space(1))) unsigned int*)g,
      (__attribute__((address_space(3))) unsigned int*)l, 16, 0, 0);
}

// ---------------- shared tile body (R10-proven: l15 swizzle, conflicts==0 verified)
template<bool DIAG>
__device__ __forceinline__ void tile_compute(
    const char* lds, const char* ldsW, const bf16x8 a[4][4],
    int C0loc, int colBase, int lane, int WR0, f32x2 acc[4][4])
{
  const int l15 = lane & 15, lg = lane >> 4;
  #pragma unroll
  for (int nf = 0; nf < 4; ++nf) {
    int col = nf * 16 + l15;
    int colg = colBase + C0loc + col;
    f32x2 wv = *(const f32x2*)(ldsW + ((C0loc + col) << 3));  // LDS broadcast
    bf16x8 b[4];
    #pragma unroll
    for (int kk = 0; kk < 4; ++kk) {
      int addr = col * 256 + (((kk * 4 + lg) ^ l15) << 4);    // 2-way banks (free)
      b[kk] = *(const bf16x8*)(lds + addr);
    }
    f32x4 c[4];
    __builtin_amdgcn_s_setprio(1);
    #pragma unroll
    for (int mf = 0; mf < 4; ++mf) {
      f32x4 t = {0.f, 0.f, 0.f, 0.f};
      #pragma unroll
      for (int kk = 0; kk < 4; ++kk)
        t = __builtin_amdgcn_mfma_f32_16x16x32_bf16(a[mf][kk], b[kk], t, 0, 0, 0);
      c[mf] = t;
    }
    __builtin_amdgcn_s_setprio(0);
    #pragma unroll
    for (int mf = 0; mf < 4; ++mf) {
      #pragma unroll
      for (int r = 0; r < 4; ++r) {
        float p = EXP2F(c[mf][r]);     // exp(sim/T), scale folded into operands
        if (DIAG) {
          int rowg = WR0 + mf * 16 + lg * 4 + r;  // verified C/D layout
          p = (rowg == colg) ? 0.0f : p;
        }
        acc[mf][r] += wv * p;          // v_pk_fma_f32: (label-0 sum, total sum)
      }
    }
  }
}

// ================= fused cooperative kernel: prep -> Gram -> loss -> reduce =================
__global__ __launch_bounds__(256, 2) void fused_kernel(
    const float* __restrict__ E, const int* __restrict__ labels,
    const int* __restrict__ mask, __hip_bfloat16* __restrict__ Ebf,
    float2* __restrict__ W, float2* __restrict__ SW,
    float2* __restrict__ partialF, int2* __restrict__ partialI,
    float* __restrict__ out)
{
  cg::grid_group grid = cg::this_grid();
  __shared__ alignas(16) char smem[49152];   // 16 KB ldsW + 32 KB tile dbuf (reused per phase)
  const int tid = threadIdx.x;
  const int bid = blockIdx.x;
  const int lane = tid & 63;
  const int w = tid >> 6;
  const int l15 = lane & 15, lg = lane >> 4;
  const int gtid = bid * 256 + tid;

  // ---------- phase 1: prep (normalize+prescale rows, W weights, histogram partials)
  if (gtid < B_N) {
    int lb = labels[gtid];
    float wm = (mask[gtid] != 0) ? 1.0f : 0.0f;
    W[gtid] = make_float2((lb == 0) ? wm : 0.0f, wm);
  }
  if (bid < 64) {   // integer histogram partials (deterministic, no atomics)
    int c0 = 0, c1 = 0;
    if (mask[gtid] != 0) { if (labels[gtid] == 0) c0 = 1; else c1 = 1; }
    #pragma unroll
    for (int m = 1; m < 64; m <<= 1) { c0 += __shfl_xor(c0, m); c1 += __shfl_xor(c1, m); }
    int* hc = (int*)smem;
    if (lane == 0) { hc[w] = c0; hc[4 + w] = c1; }
    __syncthreads();
    if (tid == 0)
      partialI[bid] = make_int2(hc[0] + hc[1] + hc[2] + hc[3],
                                hc[4] + hc[5] + hc[6] + hc[7]);
  }
  {
    int wid = gtid >> 6;   // 2048 waves, 8 rows each
    const float2* E2 = (const float2*)E;
    __hip_bfloat162* O2 = (__hip_bfloat162*)Ebf;
    for (int row = wid; row < B_N; row += 2048) {
      float2 v = E2[row * 64 + lane];
      float ss = v.x * v.x + v.y * v.y;
      #pragma unroll
      for (int m = 1; m < 64; m <<= 1) ss += __shfl_xor(ss, m);
      // sqrt(14.426950408889634) = sqrt(1/(0.1*ln2)); folded into both operands
      float sc = 3.7982826f / fmaxf(sqrtf(ss), 1e-12f);
      __hip_bfloat162 h;
      h.x = __float2bfloat16(v.x * sc);
      h.y = __float2bfloat16(v.y * sc);
      O2[row * 64 + lane] = h;
    }
  }
  grid.sync();

  // ---------- phase 2: Gram + exp + masked row-sums (R10 body; 32 tiles/block)
  {
    char* ldsW  = smem;            // 16 KB (2048 cols x 8 B)
    char* tiles = smem + 16384;    // 2 x 16 KB double buffer
    const int s = bid & 7;                 // split = XCD (bid%8 round-robin) -> L2-pinned cols
    const int R0 = (bid >> 3) * 256;
    const int WR0 = R0 + w * 64;
    const int colBase = s * CPS;

    bf16x8 a[4][4];
    #pragma unroll
    for (int mf = 0; mf < 4; ++mf)
      #pragma unroll
      for (int kk = 0; kk < 4; ++kk) {
        int row = WR0 + mf * 16 + l15;
        a[mf][kk] = *(const bf16x8*)(Ebf + (size_t)row * D_K + kk * 32 + lg * 8);
      }

    int goff[4], loff[4];
    #pragma unroll
    for (int i = 0; i < 4; ++i) {
      int q = i * 4 + w;
      int col = q * 4 + lg;
      int cc = l15 ^ (col & 15);    // inverse of the l15 read swizzle
      goff[i] = col * D_K + cc * 8;
      loff[i] = q * 1024;
    }

    f32x2 acc[4][4] = {};
    {
      const char* wsrc = (const char*)(W + colBase);
      for (int i = tid; i < (CPS >> 1); i += 256)
        gload_lds16(wsrc + i * 16, ldsW + i * 16);
      const __hip_bfloat16* src0 = Ebf + (size_t)colBase * D_K;
      #pragma unroll
      for (int i = 0; i < 4; ++i) gload_lds16(src0 + goff[i], tiles + loff[i]);
    }
    asm volatile("s_waitcnt vmcnt(0)" ::: "memory");
    __builtin_amdgcn_s_barrier();

    int cur = 0;
    for (int t = 0; t < 32; ++t) {
      if (t + 1 < 32) {
        const __hip_bfloat16* src = Ebf + (size_t)(colBase + ((t + 1) << 6)) * D_K;
        char* dst = tiles + ((cur ^ 1) << 14);
        #pragma unroll
        for (int i = 0; i < 4; ++i) gload_lds16(src + goff[i], dst + loff[i]);
      }
      const int C0loc = t << 6;
      const int Cg = colBase + C0loc;
      const bool diag = (Cg < R0 + 256) && (Cg + 64 > R0);
      if (diag) tile_compute<true >(tiles + (cur << 14), ldsW, a, C0loc, colBase, lane, WR0, acc);
      else      tile_compute<false>(tiles + (cur << 14), ldsW, a, C0loc, colBase, lane, WR0, acc);
      asm volatile("s_waitcnt vmcnt(0)" ::: "memory");
      __builtin_amdgcn_s_barrier();
      cur ^= 1;
    }

    #pragma unroll
    for (int mf = 0; mf < 4; ++mf) {
      #pragma unroll
      for (int r = 0; r < 4; ++r) {
        float s0 = acc[mf][r].x, tt = acc[mf][r].y;
        #pragma unroll
        for (int m = 1; m < 16; m <<= 1) {
          s0 += __shfl_xor(s0, m);
          tt += __shfl_xor(tt, m);
        }
        if (l15 == 0) {
          int rowg = WR0 + mf * 16 + lg * 4 + r;
          SW[(size_t)s * B_N + rowg] = make_float2(s0, tt);
        }
      }
    }
  }
  grid.sync();

  // ---------- phase 3: per-row loss (32 rows/block, 8 threads/row), block partials
  {
    int* cs = (int*)smem;                      // [2] histogram totals
    float2* red = (float2*)(smem + 64);        // 256 float2
    if (tid < 64) {
      int2 p = partialI[tid];
      int a = p.x, b = p.y;
      #pragma unroll
      for (int m = 1; m < 64; m <<= 1) { a += __shfl_xor(a, m); b += __shfl_xor(b, m); }
      if (tid == 0) { cs[0] = a; cs[1] = b; }
    }
    int rr = tid & 31, q = tid >> 5;
    int r = bid * 32 + rr;
    float2 v = SW[(size_t)q * B_N + r];        // slot q contribution for row r
    red[tid] = v;
    __syncthreads();
    int cnt0 = cs[0], cnt1 = cs[1];
    if (q == 0) {                              // threads 0..31 (wave 0)
      float s0 = 0.f, tt = 0.f;
      #pragma unroll
      for (int k = 0; k < 8; ++k) { float2 u = red[k * 32 + rr]; s0 += u.x; tt += u.y; }
      int lb = labels[r];
      float pos = (lb == 0) ? s0 : (tt - s0);
      int cnt = (lb == 0) ? cnt0 : cnt1;
      float tot = 0.f, nv = 0.f;
      if (mask[r] != 0 && cnt > 1) {
        // den = pos + neg = tt (diag excluded); loss = log(den+EPS) - log(pos)
        tot = logf(tt + 1e-8f) - logf(pos);
        nv = 1.f;
      }
      #pragma unroll
      for (int m = 1; m < 32; m <<= 1) { tot += __shfl_xor(tot, m); nv += __shfl_xor(nv, m); }
      if (tid == 0) partialF[bid] = make_float2(tot, nv);
    }
  }
  grid.sync();

  // ---------- phase 4: final deterministic reduce (block 0)
  if (bid == 0) {
    float2 x = partialF[tid], y = partialF[tid + 256];
    float t = x.x + y.x, n = x.y + y.y;
    #pragma unroll
    for (int m = 1; m < 64; m <<= 1) { t += __shfl_xor(t, m); n += __shfl_xor(n, m); }
    __syncthreads();                           // smem reuse fence
    float* fs = (float*)smem;
    if (lane == 0) { fs[w] = t; fs[4 + w] = n; }
    __syncthreads();
    if (tid == 0) {
      float T = fs[0] + fs[1] + fs[2] + fs[3];
      float N = fs[4] + fs[5] + fs[6] + fs[7];
      out[0] = (N > 0.f) ? T / fmaxf(N, 1.f) : 0.f;
    }
  }
}

// ================= legacy 4-kernel path (R10-proven fallback) =================
__global__ __launch_bounds__(256) void prep_kernel(
    const float* __restrict__ E, const int* __restrict__ labels,
    const int* __restrict__ mask, __hip_bfloat16* __restrict__ Ebf,
    float2* __restrict__ W)
{
  int tid = threadIdx.x;
  int gtid = blockIdx.x * 256 + tid;
  if (gtid < B_N) {
    int lb = labels[gtid];
    float wm = (mask[gtid] != 0) ? 1.0f : 0.0f;
    W[gtid] = make_float2((lb == 0) ? wm : 0.0f, wm);
  }
  int lane = tid & 63;
  int wid = gtid >> 6;
  const float2* E2 = (const float2*)E;
  __hip_bfloat162* O2 = (__hip_bfloat162*)Ebf;
  for (int row = wid; row < B_N; row += 4096) {
    float2 v = E2[row * 64 + lane];
    float ss = v.x * v.x + v.y * v.y;
    #pragma unroll
    for (int m = 1; m < 64; m <<= 1) ss += __shfl_xor(ss, m);
    float sc = 3.7982826f / fmaxf(sqrtf(ss), 1e-12f);
    __hip_bfloat162 h;
    h.x = __float2bfloat16(v.x * sc);
    h.y = __float2bfloat16(v.y * sc);
    O2[row * 64 + lane] = h;
  }
}

__global__ __launch_bounds__(256, 2) void gemm_kernel(
    const __hip_bfloat16* __restrict__ Ebf, const float2* __restrict__ W,
    float2* __restrict__ SW, int colsPerSplit)
{
  __shared__ alignas(16) char smem[40960];
  char* ldsW  = smem;
  char* tiles = smem + 8192;
  const int tid = threadIdx.x;
  const int lane = tid & 63;
  const int w = tid >> 6;
  const int R0 = blockIdx.x * 256;
  const int WR0 = R0 + w * 64;
  const int l15 = lane & 15, lg = lane >> 4;

  bf16x8 a[4][4];
  #pragma unroll
  for (int mf = 0; mf < 4; ++mf)
    #pragma unroll
    for (int kk = 0; kk < 4; ++kk) {
      int row = WR0 + mf * 16 + l15;
      a[mf][kk] = *(const bf16x8*)(Ebf + (size_t)row * D_K + kk * 32 + lg * 8);
    }
  int goff[4], loff[4];
  #pragma unroll
  for (int i = 0; i < 4; ++i) {
    int q = i * 4 + w;
    int col = q * 4 + lg;
    int cc = l15 ^ (col & 15);
    goff[i] = col * D_K + cc * 8;
    loff[i] = q * 1024;
  }
  f32x2 acc[4][4] = {};
  const int colBase = blockIdx.y * colsPerSplit;
  const int nt = colsPerSplit >> 6;
  {
    const char* wsrc = (const char*)(W + colBase);
    for (int i = tid; i < (colsPerSplit >> 1); i += 256)
      gload_lds16(wsrc + i * 16, ldsW + i * 16);
    const __hip_bfloat16* src0 = Ebf + (size_t)colBase * D_K;
    #pragma unroll
    for (int i = 0; i < 4; ++i) gload_lds16(src0 + goff[i], tiles + loff[i]);
  }
  asm volatile("s_waitcnt vmcnt(0)" ::: "memory");
  __builtin_amdgcn_s_barrier();
  int cur = 0;
  for (int t = 0; t < nt; ++t) {
    if (t + 1 < nt) {
      const __hip_bfloat16* src = Ebf + (size_t)(colBase + ((t + 1) << 6)) * D_K;
      #pragma unroll
      for (int i = 0; i < 4; ++i) gload_lds16(src + goff[i], tiles + ((cur ^ 1) << 14) + loff[i]);
    }
    const int C0loc = t << 6;
    const int Cg = colBase + C0loc;
    const bool diag = (Cg < R0 + 256) && (Cg + 64 > R0);
    if (diag) tile_compute<true >(tiles + (cur << 14), ldsW, a, C0loc, colBase, lane, WR0, acc);
    else      tile_compute<false>(tiles + (cur << 14), ldsW, a, C0loc, colBase, lane, WR0, acc);
    asm volatile("s_waitcnt vmcnt(0)" ::: "memory");
    __builtin_amdgcn_s_barrier();
    cur ^= 1;
  }
  #pragma unroll
  for (int mf = 0; mf < 4; ++mf) {
    #pragma unroll
    for (int r = 0; r < 4; ++r) {
      float s0 = acc[mf][r].x, tt = acc[mf][r].y;
      #pragma unroll
      for (int m = 1; m < 16; m <<= 1) { s0 += __shfl_xor(s0, m); tt += __shfl_xor(tt, m); }
      if (l15 == 0) {
        int rowg = WR0 + mf * 16 + lg * 4 + r;
        SW[(size_t)blockIdx.y * B_N + rowg] = make_float2(s0, tt);
      }
    }
  }
}

__global__ __launch_bounds__(256) void loss_part(
    const int* __restrict__ labels, const int* __restrict__ mask,
    const float2* __restrict__ SW, int NS, float2* __restrict__ partial)
{
  __shared__ int sc0[4], sc1[4];
  __shared__ float st[4], sn[4];
  __shared__ float2 red[256];
  int tid = threadIdx.x, lane = tid & 63, wv = tid >> 6;

  int c0 = 0, c1 = 0;
  for (int i = tid; i < B_N; i += 256) {
    if (mask[i] != 0) { if (labels[i] == 0) c0++; else c1++; }
  }
  #pragma unroll
  for (int m = 1; m < 64; m <<= 1) { c0 += __shfl_xor(c0, m); c1 += __shfl_xor(c1, m); }
  if (lane == 0) { sc0[wv] = c0; sc1[wv] = c1; }
  __syncthreads();
  int cnt0 = sc0[0] + sc0[1] + sc0[2] + sc0[3];
  int cnt1 = sc1[0] + sc1[1] + sc1[2] + sc1[3];

  int r = blockIdx.x * 64 + (tid & 63);
  int q = tid >> 6;
  float s0 = 0.f, tt = 0.f;
  for (int s = q; s < NS; s += 4) {
    float2 v = SW[(size_t)s * B_N + r];
    s0 += v.x; tt += v.y;
  }
  red[tid] = make_float2(s0, tt);
  __syncthreads();

  float tot = 0.f, nv = 0.f;
  if (q == 0) {
    float2 va = red[tid], vb = red[64 + tid], vc = red[128 + tid], vd = red[192 + tid];
    s0 = va.x + vb.x + vc.x + vd.x;
    tt = va.y + vb.y + vc.y + vd.y;
    int lb = labels[r];
    float pos = (lb == 0) ? s0 : (tt - s0);
    int cnt = (lb == 0) ? cnt0 : cnt1;
    if (mask[r] != 0 && cnt > 1) {
      tot = logf(tt + 1e-8f) - logf(pos);
      nv = 1.f;
    }
  }
  #pragma unroll
  for (int m = 1; m < 64; m <<= 1) { tot += __shfl_xor(tot, m); nv += __shfl_xor(nv, m); }
  if (lane == 0) { st[wv] = tot; sn[wv] = nv; }
  __syncthreads();
  if (tid == 0) {
    partial[blockIdx.x] = make_float2(st[0] + st[1] + st[2] + st[3],
                                      sn[0] + sn[1] + sn[2] + sn[3]);
  }
}

__global__ __launch_bounds__(64) void loss_final(
    const float2* __restrict__ partial, int nb, float* __restrict__ out)
{
  int lane = threadIdx.x;
  float t = 0.f, n = 0.f;
  for (int i = lane; i < nb; i += 64) {
    float2 v = partial[i];
    t += v.x; n += v.y;
  }
  #pragma unroll
  for (int m = 1; m < 64; m <<= 1) { t += __shfl_xor(t, m); n += __shfl_xor(n, m); }
  if (lane == 0) out[0] = (n > 0.f) ? t / fmaxf(n, 1.f) : 0.f;
}

extern "C" void kernel_launch(void* const* d_in, const int* in_sizes, int n_in,
                              void* d_out, int out_size, void* d_ws, size_t ws_size,
                              hipStream_t stream)
{
  const float* E = (const float*)d_in[0];
  const int* labels = (const int*)d_in[1];
  const int* mask = (const int*)d_in[2];

  char* ws = (char*)d_ws;
  __hip_bfloat16* Ebf = (__hip_bfloat16*)ws;                       // 4 MB
  float2* W = (float2*)(ws + (size_t)B_N * D_K * 2);               // 128 KB
  float2* SW = (float2*)(ws + (size_t)B_N * D_K * 2 + (size_t)B_N * 8);
  size_t base = (size_t)B_N * D_K * 2 + (size_t)B_N * 8;

  size_t needF = base + (size_t)16 * B_N * 8 + FGRID * 8 + 64 * 8 + 64;
  bool launched = false;
  if (ws_size >= needF) {
    float2* partialF = (float2*)(ws + base + (size_t)16 * B_N * 8);
    int2* partialI = (int2*)((char*)partialF + FGRID * 8);
    float* outp = (float*)d_out;
    void* args[] = {(void*)&E, (void*)&labels, (void*)&mask, (void*)&Ebf,
                    (void*)&W, (void*)&SW, (void*)&partialF, (void*)&partialI,
                    (void*)&outp};
    hipError_t err = hipLaunchCooperativeKernel((void*)fused_kernel,
                                                dim3(FGRID), dim3(256),
                                                args, 0, stream);
    launched = (err == hipSuccess);
  }

  if (!launched) {
    // legacy 4-kernel path (R10, 126 us e2e)
    int NS = 16;
    while (NS > 1 && base + (size_t)NS * B_N * 8 + 4096 > ws_size) NS >>= 1;
    int cps = B_N / NS;
    float2* partial = (float2*)(ws + base + (size_t)NS * B_N * 8);
    prep_kernel<<<1024, 256, 0, stream>>>(E, labels, mask, Ebf, W);
    dim3 g2(B_N / 256, NS);
    gemm_kernel<<<g2, 256, 0, stream>>>(Ebf, W, SW, cps);
    loss_part<<<B_N / 64, 256, 0, stream>>>(labels, mask, SW, NS, partial);
    loss_final<<<1, 64, 0, stream>>>(partial, B_N / 64, (float*)d_out);
  }
}

// Round 14
// 125.371 us; speedup vs baseline: 2.0565x; 2.0565x over previous
//
#include <hip/hip_runtime.h>
#include <hip/hip_bf16.h>

#define B_N 16384
#define D_K 128
#define NS_DEF 8   // col splits: 512 blocks = exactly one 2-blocks/CU round

typedef __bf16 bf16x8 __attribute__((ext_vector_type(8)));
typedef float f32x4 __attribute__((ext_vector_type(4)));
typedef float f32x2 __attribute__((ext_vector_type(2)));

#if defined(__has_builtin)
#if __has_builtin(__builtin_amdgcn_exp2f)
#define EXP2F(x) __builtin_amdgcn_exp2f(x)
#else
#define EXP2F(x) exp2f(x)
#endif
#else
#define EXP2F(x) exp2f(x)
#endif

__device__ __forceinline__ void gload_lds16(const void* g, void* l) {
  __builtin_amdgcn_global_load_lds(
      (const __attribute__((address_space(1))) unsigned int*)g,
      (__attribute__((address_space(3))) unsigned int*)l, 16, 0, 0);
}

// ---------------- kernel 1: normalize rows, prescale by sqrt(1/(T*ln2)), build col
// weights; also zeroes the loss-completion counter (graph-replay safe).
__global__ __launch_bounds__(256) void prep_kernel(
    const float* __restrict__ E, const int* __restrict__ labels,
    const int* __restrict__ mask, __hip_bfloat16* __restrict__ Ebf,
    float2* __restrict__ W, unsigned int* __restrict__ counter)
{
  int tid = threadIdx.x;
  int gtid = blockIdx.x * 256 + tid;
  if (gtid == 0) *counter = 0u;
  if (gtid < B_N) {
    int lb = labels[gtid];
    float wm = (mask[gtid] != 0) ? 1.0f : 0.0f;
    W[gtid] = make_float2((lb == 0) ? wm : 0.0f, wm);
  }
  int lane = tid & 63;
  int wid = gtid >> 6;
  const float2* E2 = (const float2*)E;
  __hip_bfloat162* O2 = (__hip_bfloat162*)Ebf;
  for (int row = wid; row < B_N; row += 4096) {
    float2 v = E2[row * 64 + lane];
    float ss = v.x * v.x + v.y * v.y;
    #pragma unroll
    for (int m = 1; m < 64; m <<= 1) ss += __shfl_xor(ss, m);
    // sqrt(14.426950408889634) = sqrt(1/(0.1*ln2)); folded into both operands
    float sc = 3.7982826f / fmaxf(sqrtf(ss), 1e-12f);
    __hip_bfloat162 h;
    h.x = __float2bfloat16(v.x * sc);
    h.y = __float2bfloat16(v.y * sc);
    O2[row * 64 + lane] = h;
  }
}

// ---------------- kernel 2: fused Gram + exp + masked row-sum (R10-proven body)
// l15 swizzle: bank conflicts == 0 (verified R10). W in LDS. One barrier/tile.
template<bool DIAG>
__device__ __forceinline__ void tile_compute(
    const char* lds, const char* ldsW, const bf16x8 a[4][4],
    int C0loc, int colBase, int lane, int WR0, f32x2 acc[4][4])
{
  const int l15 = lane & 15, lg = lane >> 4;
  #pragma unroll
  for (int nf = 0; nf < 4; ++nf) {
    int col = nf * 16 + l15;
    int colg = colBase + C0loc + col;
    f32x2 wv = *(const f32x2*)(ldsW + ((C0loc + col) << 3));  // LDS broadcast
    bf16x8 b[4];
    #pragma unroll
    for (int kk = 0; kk < 4; ++kk) {
      int addr = col * 256 + (((kk * 4 + lg) ^ l15) << 4);    // 2-way banks (free)
      b[kk] = *(const bf16x8*)(lds + addr);
    }
    f32x4 c[4];
    __builtin_amdgcn_s_setprio(1);
    #pragma unroll
    for (int mf = 0; mf < 4; ++mf) {
      f32x4 t = {0.f, 0.f, 0.f, 0.f};
      #pragma unroll
      for (int kk = 0; kk < 4; ++kk)
        t = __builtin_amdgcn_mfma_f32_16x16x32_bf16(a[mf][kk], b[kk], t, 0, 0, 0);
      c[mf] = t;
    }
    __builtin_amdgcn_s_setprio(0);
    #pragma unroll
    for (int mf = 0; mf < 4; ++mf) {
      #pragma unroll
      for (int r = 0; r < 4; ++r) {
        float p = EXP2F(c[mf][r]);     // exp(sim/T), scale folded into operands
        if (DIAG) {
          int rowg = WR0 + mf * 16 + lg * 4 + r;  // verified C/D layout
          p = (rowg == colg) ? 0.0f : p;
        }
        acc[mf][r] += wv * p;          // v_pk_fma_f32: (label-0 sum, total sum)
      }
    }
  }
}

// (256,2) = 256-reg unified budget; 64-row/wave live ~176 regs.
// (256,3)/(256,4) spill catastrophically (R1/R3). Flat across sync variants
// (R2/R5/R10/R12) -> this is the plateau structure; NS=8 trims rounds/amortization.
__global__ __launch_bounds__(256, 2) void gemm_kernel(
    const __hip_bfloat16* __restrict__ Ebf, const float2* __restrict__ W,
    float2* __restrict__ SW, int colsPerSplit)
{
  __shared__ alignas(16) char smem[49152];
  char* ldsW  = smem;            // 16 KB: w(col) for cps<=2048
  char* tiles = smem + 16384;    // 2 x 16 KB double buffer

  const int tid = threadIdx.x;
  const int lane = tid & 63;
  const int w = tid >> 6;
  const int R0 = blockIdx.x * 256;
  const int WR0 = R0 + w * 64;
  const int l15 = lane & 15, lg = lane >> 4;

  // A fragments: 4 m-frags x 4 k-steps, held in VGPRs for the whole col loop
  bf16x8 a[4][4];
  #pragma unroll
  for (int mf = 0; mf < 4; ++mf)
    #pragma unroll
    for (int kk = 0; kk < 4; ++kk) {
      int row = WR0 + mf * 16 + l15;
      a[mf][kk] = *(const bf16x8*)(Ebf + (size_t)row * D_K + kk * 32 + lg * 8);
    }

  // staging offsets: linear LDS dest, full-4-bit inverse swizzle on global source
  int goff[4], loff[4];
  #pragma unroll
  for (int i = 0; i < 4; ++i) {
    int q = i * 4 + w;            // 1KB chunk-group id 0..15 (16KB tile)
    int col = q * 4 + lg;         // tile-local col this lane feeds (0..63)
    int cc = l15 ^ (col & 15);    // inverse of the l15 read swizzle
    goff[i] = col * D_K + cc * 8; // bf16 elements
    loff[i] = q * 1024;           // wave-uniform LDS base (bytes)
  }

  f32x2 acc[4][4] = {};
  const int colBase = blockIdx.y * colsPerSplit;
  const int nt = colsPerSplit >> 6;

  // prologue: stage W slice + tile 0, drain, rendezvous
  {
    const char* wsrc = (const char*)(W + colBase);
    for (int i = tid; i < (colsPerSplit >> 1); i += 256)
      gload_lds16(wsrc + i * 16, ldsW + i * 16);
    const __hip_bfloat16* src0 = Ebf + (size_t)colBase * D_K;
    #pragma unroll
    for (int i = 0; i < 4; ++i) gload_lds16(src0 + goff[i], tiles + loff[i]);
  }
  asm volatile("s_waitcnt vmcnt(0)" ::: "memory");
  __builtin_amdgcn_s_barrier();

  int cur = 0;
  for (int t = 0; t < nt; ++t) {
    if (t + 1 < nt) {   // prefetch next tile into the other buffer (2-phase)
      const __hip_bfloat16* src = Ebf + (size_t)(colBase + ((t + 1) << 6)) * D_K;
      char* dst = tiles + ((cur ^ 1) << 14);
      #pragma unroll
      for (int i = 0; i < 4; ++i) gload_lds16(src + goff[i], dst + loff[i]);
    }
    const int C0loc = t << 6;
    const int Cg = colBase + C0loc;
    const bool diag = (Cg < R0 + 256) && (Cg + 64 > R0);
    if (diag) tile_compute<true >(tiles + (cur << 14), ldsW, a, C0loc, colBase, lane, WR0, acc);
    else      tile_compute<false>(tiles + (cur << 14), ldsW, a, C0loc, colBase, lane, WR0, acc);
    asm volatile("s_waitcnt vmcnt(0)" ::: "memory");
    __builtin_amdgcn_s_barrier();
    cur ^= 1;
  }

  // reduce the 16 lanes (same row-group, different col subsets), then store
  #pragma unroll
  for (int mf = 0; mf < 4; ++mf) {
    #pragma unroll
    for (int r = 0; r < 4; ++r) {
      float s0 = acc[mf][r].x, tt = acc[mf][r].y;
      #pragma unroll
      for (int m = 1; m < 16; m <<= 1) {
        s0 += __shfl_xor(s0, m);
        tt += __shfl_xor(tt, m);
      }
      if (l15 == 0) {
        int rowg = WR0 + mf * 16 + lg * 4 + r;
        SW[(size_t)blockIdx.y * B_N + rowg] = make_float2(s0, tt);
      }
    }
  }
}

// ---------------- kernel 3: per-row loss + last-block final reduce (fused)
// 256 blocks x 64 rows. Each block writes a partial, fences, bumps the counter;
// the 256th arrival re-reads all partials in FIXED index order (bit-deterministic).
__global__ __launch_bounds__(256) void loss_kernel(
    const int* __restrict__ labels, const int* __restrict__ mask,
    const float2* __restrict__ SW, int NS, float2* __restrict__ partial,
    unsigned int* __restrict__ counter, float* __restrict__ out)
{
  __shared__ int sc0[4], sc1[4];
  __shared__ float st[4], sn[4];
  __shared__ float2 red[256];
  __shared__ unsigned int sLast;
  int tid = threadIdx.x, lane = tid & 63, wv = tid >> 6;

  // redundant full histogram per block (L2-resident, deterministic)
  int c0 = 0, c1 = 0;
  for (int i = tid; i < B_N; i += 256) {
    if (mask[i] != 0) { if (labels[i] == 0) c0++; else c1++; }
  }
  #pragma unroll
  for (int m = 1; m < 64; m <<= 1) { c0 += __shfl_xor(c0, m); c1 += __shfl_xor(c1, m); }
  if (lane == 0) { sc0[wv] = c0; sc1[wv] = c1; }
  __syncthreads();
  int cnt0 = sc0[0] + sc0[1] + sc0[2] + sc0[3];
  int cnt1 = sc1[0] + sc1[1] + sc1[2] + sc1[3];

  // 64 rows per block; 4 threads per row (slot quarters), fixed-order combine
  int r = blockIdx.x * 64 + (tid & 63);
  int q = tid >> 6;
  float s0 = 0.f, tt = 0.f;
  for (int s = q; s < NS; s += 4) {
    float2 v = SW[(size_t)s * B_N + r];
    s0 += v.x; tt += v.y;
  }
  red[tid] = make_float2(s0, tt);
  __syncthreads();

  float tot = 0.f, nv = 0.f;
  if (q == 0) {
    float2 va = red[tid], vb = red[64 + tid], vc = red[128 + tid], vd = red[192 + tid];
    s0 = va.x + vb.x + vc.x + vd.x;
    tt = va.y + vb.y + vc.y + vd.y;
    int lb = labels[r];
    float pos = (lb == 0) ? s0 : (tt - s0);
    int cnt = (lb == 0) ? cnt0 : cnt1;
    if (mask[r] != 0 && cnt > 1) {
      // den = pos + neg = tt (diag excluded); loss = log(den+EPS) - log(pos)
      tot = logf(tt + 1e-8f) - logf(pos);
      nv = 1.f;
    }
  }
  #pragma unroll
  for (int m = 1; m < 64; m <<= 1) { tot += __shfl_xor(tot, m); nv += __shfl_xor(nv, m); }
  if (lane == 0) { st[wv] = tot; sn[wv] = nv; }
  __syncthreads();
  if (tid == 0) {
    partial[blockIdx.x] = make_float2(st[0] + st[1] + st[2] + st[3],
                                      sn[0] + sn[1] + sn[2] + sn[3]);
    __threadfence();                                  // partial visible device-wide
    sLast = atomicAdd(counter, 1u);                   // device-scope arrival ticket
  }
  __syncthreads();
  if (sLast == 255u) {                                // last block finalizes
    __threadfence();                                  // all partials visible
    if (tid < 64) {
      float2 x0 = partial[tid],        x1 = partial[64 + tid];
      float2 x2 = partial[128 + tid],  x3 = partial[192 + tid];
      float t = x0.x + x1.x + x2.x + x3.x;
      float n = x0.y + x1.y + x2.y + x3.y;
      #pragma unroll
      for (int m = 1; m < 64; m <<= 1) { t += __shfl_xor(t, m); n += __shfl_xor(n, m); }
      if (tid == 0) out[0] = (n > 0.f) ? t / fmaxf(n, 1.f) : 0.f;
    }
  }
}

extern "C" void kernel_launch(void* const* d_in, const int* in_sizes, int n_in,
                              void* d_out, int out_size, void* d_ws, size_t ws_size,
                              hipStream_t stream)
{
  const float* E = (const float*)d_in[0];
  const int* labels = (const int*)d_in[1];
  const int* mask = (const int*)d_in[2];

  char* ws = (char*)d_ws;
  __hip_bfloat16* Ebf = (__hip_bfloat16*)ws;                       // 4 MB
  float2* W = (float2*)(ws + (size_t)B_N * D_K * 2);               // 128 KB
  float2* SW = (float2*)(ws + (size_t)B_N * D_K * 2 + (size_t)B_N * 8);
  size_t base = (size_t)B_N * D_K * 2 + (size_t)B_N * 8;

  int NS = NS_DEF;  // shrink if workspace tight (ldsW sized for cps<=2048)
  while (NS > 1 && base + (size_t)NS * B_N * 8 + 4096 > ws_size) NS >>= 1;
  int cps = B_N / NS;
  float2* partial = (float2*)(ws + base + (size_t)NS * B_N * 8);
  unsigned int* counter = (unsigned int*)((char*)partial + 256 * 8);

  prep_kernel<<<1024, 256, 0, stream>>>(E, labels, mask, Ebf, W, counter);
  dim3 g2(B_N / 256, NS);   // (64, 8) = 512 blocks = one full 2-blocks/CU round
  gemm_kernel<<<g2, 256, 0, stream>>>(Ebf, W, SW, cps);
  loss_kernel<<<B_N / 64, 256, 0, stream>>>(labels, mask, SW, NS, partial,
                                            counter, (float*)d_out);
}